// Round 5
// baseline (693.928 us; speedup 1.0000x reference)
//
#include <hip/hip_runtime.h>
#include <hip/hip_fp16.h>

#define N_NODES 100000
#define N_EDGES 1600000
#define F 64
#define NCLS 16
#define K1 8

using f16x8 = __attribute__((ext_vector_type(8))) _Float16;
using f32x4 = __attribute__((ext_vector_type(4))) float;

// ---------------- degree / normalization ----------------

__global__ void k_deg(const int* __restrict__ ei, int* __restrict__ deg) {
    int e = blockIdx.x * blockDim.x + threadIdx.x;
    if (e >= N_EDGES) return;
    int r = ei[e], c = ei[N_EDGES + e];
    if (r != c) atomicAdd(&deg[r], 1);
}

__global__ void k_dinv(const int* __restrict__ deg, float* __restrict__ dinv) {
    int i = blockIdx.x * blockDim.x + threadIdx.x;
    if (i >= N_NODES) return;
    int d = deg[i];
    dinv[i] = d > 0 ? rsqrtf((float)d) : 0.f;
}

// ---------------- exclusive scan (rowptr) ----------------
__global__ void k_scan1(const int* __restrict__ deg, int* __restrict__ rowptr, int* __restrict__ bsum) {
    __shared__ int sd[256];
    int tid = threadIdx.x;
    int base = blockIdx.x * 1024 + tid * 4;
    int v[4];
#pragma unroll
    for (int j = 0; j < 4; j++) {
        int idx = base + j;
        v[j] = (idx < N_NODES) ? deg[idx] : 0;
    }
    int s = v[0] + v[1] + v[2] + v[3];
    sd[tid] = s;
    __syncthreads();
    for (int d = 1; d < 256; d <<= 1) {
        int t = (tid >= d) ? sd[tid - d] : 0;
        __syncthreads();
        sd[tid] += t;
        __syncthreads();
    }
    int excl = sd[tid] - s;
    if (tid == 255) bsum[blockIdx.x] = sd[255];
    int run = excl;
#pragma unroll
    for (int j = 0; j < 4; j++) {
        int idx = base + j;
        if (idx < N_NODES) rowptr[idx] = run;
        run += v[j];
    }
}

__global__ void k_scan2(int* __restrict__ bsum, int* __restrict__ rowptr, int nblk) {
    if (threadIdx.x == 0 && blockIdx.x == 0) {
        int acc = 0;
        for (int b = 0; b < nblk; b++) { int t = bsum[b]; bsum[b] = acc; acc += t; }
        rowptr[N_NODES] = acc;
    }
}

__global__ void k_scan3(int* __restrict__ rowptr, const int* __restrict__ bsum) {
    int tid = threadIdx.x;
    int base = blockIdx.x * 1024 + tid * 4;
    int off = bsum[blockIdx.x];
#pragma unroll
    for (int j = 0; j < 4; j++) {
        int idx = base + j;
        if (idx < N_NODES) rowptr[idx] += off;
    }
}

// ---------------- CSR fill: col only (4 B per edge) ----------------
__global__ void k_fill(const int* __restrict__ ei,
                       const int* __restrict__ rowptr, int* __restrict__ cursor,
                       int* __restrict__ csr_col) {
    int e = blockIdx.x * blockDim.x + threadIdx.x;
    if (e >= N_EDGES) return;
    int r = ei[e], c = ei[N_EDGES + e];
    if (r == c) return;
    int p = rowptr[r] + atomicAdd(&cursor[r], 1);
    csr_col[p] = c;
}

// ---------------- x fp32 -> fp16 ----------------
__global__ void k_cvt(const float* __restrict__ x, __half* __restrict__ t0) {
    int i = blockIdx.x * blockDim.x + threadIdx.x;
    int base = i * 4;
    if (base >= N_NODES * F) return;
    float4 v = *(const float4*)&x[base];
    __half2 a = __floats2half2_rn(v.x, v.y);
    __half2 b = __floats2half2_rn(v.z, v.w);
    *(__half2*)&t0[base] = a;
    *(__half2*)&t0[base + 2] = b;
}

// ---------------- W1 -> fp16 B-fragment layout ----------------
__global__ void k_prepW(const float* __restrict__ W1, __half* __restrict__ Wf) {
    int t = blockIdx.x * blockDim.x + threadIdx.x;
    if (t >= K1 * 2 * 4 * 64) return;
    int lane = t & 63;
    int cb = (t >> 6) & 3;
    int fg = (t >> 8) & 1;
    int kidx = t >> 9;
    int col = cb * 16 + (lane & 15);
    int kbase = fg * 32 + (lane >> 4) * 8;
    f16x8 v;
#pragma unroll
    for (int j = 0; j < 8; j++)
        v[j] = (_Float16)W1[kidx * 4096 + (kbase + j) * 64 + col];
    *(f16x8*)(Wf + (size_t)t * 8) = v;
}

// ---------------- propagation: dst = alpha*(L_hat @ src) - beta*prev ----------------
// one wave per node, lane = feature. 4 B col records loaded 64-at-a-time coalesced;
// per-lane dinv gather once per chunk; 16 outstanding row gathers (zero-padded).
__global__ __launch_bounds__(256) void k_prop(const int* __restrict__ rowptr,
                                              const int* __restrict__ csr_col,
                                              const float* __restrict__ dinv,
                                              const __half* __restrict__ src,
                                              const __half* __restrict__ prev,
                                              __half* __restrict__ dst,
                                              float alpha, float beta) {
    int wid = (int)((blockIdx.x * blockDim.x + threadIdx.x) >> 6);
    int lane = threadIdx.x & 63;
    if (wid >= N_NODES) return;
    int beg = rowptr[wid], end = rowptr[wid + 1];
    float ndr = -alpha * dinv[wid];  // fold alpha and the row factor

    float acc0 = 0.f, acc1 = 0.f, acc2 = 0.f, acc3 = 0.f;

    for (int cb = beg; cb < end; cb += 64) {
        int n = end - cb;
        if (n > 64) n = 64;
        int e = 0;
        float dv = 0.f;
        if (lane < n) {
            e = csr_col[cb + lane];
            dv = dinv[e];
        }
        for (int j = 0; j < n; j += 16) {
            int cc[16];
            float ww[16];
#pragma unroll
            for (int u = 0; u < 16; u++) {
                cc[u] = __shfl(e, j + u, 64);
                ww[u] = __shfl(dv, j + u, 64);
            }
            float vv[16];
#pragma unroll
            for (int u = 0; u < 16; u++)
                vv[u] = __half2float(src[(size_t)cc[u] * F + lane]);
#pragma unroll
            for (int u = 0; u < 16; u++) {
                float w = ndr * ww[u];
                if ((u & 3) == 0) acc0 = fmaf(w, vv[u], acc0);
                else if ((u & 3) == 1) acc1 = fmaf(w, vv[u], acc1);
                else if ((u & 3) == 2) acc2 = fmaf(w, vv[u], acc2);
                else acc3 = fmaf(w, vv[u], acc3);
            }
        }
    }

    float res = (acc0 + acc1) + (acc2 + acc3);
    if (beta != 0.f) res -= beta * __half2float(prev[(size_t)wid * F + lane]);
    dst[(size_t)wid * F + lane] = __float2half(res);
}

// ---------------- fused MFMA: y = softmax(relu(sum_k Tk@W1k + b1) @ W2 + b2) ----------------
__global__ __launch_bounds__(256) void k_fused_mfma(const __half* __restrict__ T,
                                                    const __half* __restrict__ Wf,
                                                    const float* __restrict__ b1,
                                                    const float* __restrict__ W2,
                                                    const float* __restrict__ b2,
                                                    float* __restrict__ y) {
    __shared__ float Ht[64][65];
    __shared__ float W2l[64 * 16];
    __shared__ float b2l[16];
    int tid = threadIdx.x;
    int lane = tid & 63;
    int w = tid >> 6;
    int ln15 = lane & 15;
    int lg = lane >> 4;
    int base = blockIdx.x * 64;

    for (int j = tid; j < 64 * 16; j += 256) W2l[j] = W2[j];
    if (tid < 16) b2l[tid] = b2[tid];

    int nd = base + (w << 4) + ln15;
    if (nd > N_NODES - 1) nd = N_NODES - 1;  // clamp: garbage rows, stores guarded

    f32x4 acc0 = {0.f, 0.f, 0.f, 0.f};
    f32x4 acc1 = {0.f, 0.f, 0.f, 0.f};
    f32x4 acc2 = {0.f, 0.f, 0.f, 0.f};
    f32x4 acc3 = {0.f, 0.f, 0.f, 0.f};

    for (int s = 0; s < 16; s++) {
        int kidx = s >> 1;
        int fg = s & 1;
        f16x8 a = *(const f16x8*)(T + ((size_t)kidx * N_NODES + nd) * F + fg * 32 + lg * 8);
        const __half* wb = Wf + ((size_t)((kidx * 2 + fg) * 4) * 64 + lane) * 8;
        f16x8 b0 = *(const f16x8*)(wb);
        f16x8 b1f = *(const f16x8*)(wb + 64 * 8);
        f16x8 b2f = *(const f16x8*)(wb + 128 * 8);
        f16x8 b3f = *(const f16x8*)(wb + 192 * 8);
        acc0 = __builtin_amdgcn_mfma_f32_16x16x32_f16(a, b0, acc0, 0, 0, 0);
        acc1 = __builtin_amdgcn_mfma_f32_16x16x32_f16(a, b1f, acc1, 0, 0, 0);
        acc2 = __builtin_amdgcn_mfma_f32_16x16x32_f16(a, b2f, acc2, 0, 0, 0);
        acc3 = __builtin_amdgcn_mfma_f32_16x16x32_f16(a, b3f, acc3, 0, 0, 0);
    }

    int hrow = (w << 4) + (lg << 2);
    {
        float bb0 = b1[0 * 16 + ln15];
        float bb1 = b1[1 * 16 + ln15];
        float bb2 = b1[2 * 16 + ln15];
        float bb3 = b1[3 * 16 + ln15];
#pragma unroll
        for (int r = 0; r < 4; r++) {
            float h0 = acc0[r] + bb0;
            float h1 = acc1[r] + bb1;
            float h2 = acc2[r] + bb2;
            float h3 = acc3[r] + bb3;
            Ht[hrow + r][0 * 16 + ln15] = h0 > 0.f ? h0 : 0.f;
            Ht[hrow + r][1 * 16 + ln15] = h1 > 0.f ? h1 : 0.f;
            Ht[hrow + r][2 * 16 + ln15] = h2 > 0.f ? h2 : 0.f;
            Ht[hrow + r][3 * 16 + ln15] = h3 > 0.f ? h3 : 0.f;
        }
    }
    __syncthreads();

    int node = tid >> 2;
    int cg = tid & 3;
    int gnode = base + node;
    if (gnode >= N_NODES) return;
    float l0 = b2l[cg * 4 + 0], l1 = b2l[cg * 4 + 1], l2 = b2l[cg * 4 + 2], l3 = b2l[cg * 4 + 3];
    for (int f = 0; f < 64; f++) {
        float h = Ht[node][f];
        l0 = fmaf(h, W2l[f * 16 + cg * 4 + 0], l0);
        l1 = fmaf(h, W2l[f * 16 + cg * 4 + 1], l1);
        l2 = fmaf(h, W2l[f * 16 + cg * 4 + 2], l2);
        l3 = fmaf(h, W2l[f * 16 + cg * 4 + 3], l3);
    }
    float m = fmaxf(fmaxf(l0, l1), fmaxf(l2, l3));
    m = fmaxf(m, __shfl_xor(m, 1, 64));
    m = fmaxf(m, __shfl_xor(m, 2, 64));
    float e0 = expf(l0 - m), e1 = expf(l1 - m), e2 = expf(l2 - m), e3 = expf(l3 - m);
    float s = e0 + e1 + e2 + e3;
    s += __shfl_xor(s, 1, 64);
    s += __shfl_xor(s, 2, 64);
    float inv = 1.f / s;
    float4 o = make_float4(e0 * inv, e1 * inv, e2 * inv, e3 * inv);
    *(float4*)&y[(size_t)gnode * 16 + cg * 4] = o;
}

// ---------------- launch ----------------

extern "C" void kernel_launch(void* const* d_in, const int* in_sizes, int n_in,
                              void* d_out, int out_size, void* d_ws, size_t ws_size,
                              hipStream_t stream) {
    const float* x  = (const float*)d_in[0];
    const int*   ei = (const int*)d_in[1];
    const float* W1 = (const float*)d_in[2];
    const float* b1 = (const float*)d_in[3];
    const float* W2 = (const float*)d_in[4];
    const float* b2 = (const float*)d_in[5];
    float* y = (float*)d_out;

    char* p = (char*)d_ws;
    auto alloc = [&](size_t bytes) {
        char* q = p;
        p += (bytes + 255) & ~(size_t)255;
        return q;
    };
    int*   deg     = (int*)alloc((size_t)N_NODES * 4);
    float* dinv    = (float*)alloc((size_t)N_NODES * 4);
    int*   rowptr  = (int*)alloc((size_t)(N_NODES + 1) * 4);
    int*   bsum    = (int*)alloc(128 * 4);
    int*   cursor  = (int*)alloc((size_t)N_NODES * 4);
    int*   csr_col = (int*)alloc((size_t)N_EDGES * 4);
    __half* T      = (__half*)alloc((size_t)K1 * N_NODES * F * 2);
    __half* Wf     = (__half*)alloc((size_t)K1 * 2 * 4 * 64 * 8 * 2);

    hipMemsetAsync(deg, 0, (size_t)N_NODES * 4, stream);
    hipMemsetAsync(cursor, 0, (size_t)N_NODES * 4, stream);

    int eb = (N_EDGES + 255) / 256;
    int nb = (N_NODES + 255) / 256;
    k_deg<<<eb, 256, 0, stream>>>(ei, deg);
    k_dinv<<<nb, 256, 0, stream>>>(deg, dinv);
    int nblk = (N_NODES + 1023) / 1024;
    k_scan1<<<nblk, 256, 0, stream>>>(deg, rowptr, bsum);
    k_scan2<<<1, 64, 0, stream>>>(bsum, rowptr, nblk);
    k_scan3<<<nblk, 256, 0, stream>>>(rowptr, bsum);
    k_fill<<<eb, 256, 0, stream>>>(ei, rowptr, cursor, csr_col);
    k_prepW<<<16, 256, 0, stream>>>(W1, Wf);

    const size_t TSZ = (size_t)N_NODES * F;
    __half* Tk[K1];
    for (int k = 0; k < K1; k++) Tk[k] = T + (size_t)k * TSZ;

    k_cvt<<<(N_NODES * F / 4 + 255) / 256, 256, 0, stream>>>(x, Tk[0]);

    int prop_blocks = (N_NODES + 3) / 4;
    k_prop<<<prop_blocks, 256, 0, stream>>>(rowptr, csr_col, dinv, Tk[0], Tk[0], Tk[1], 1.f, 0.f);
    for (int k = 2; k < K1; k++)
        k_prop<<<prop_blocks, 256, 0, stream>>>(rowptr, csr_col, dinv, Tk[k - 1], Tk[k - 2], Tk[k], 2.f, 1.f);

    int gemm_blocks = (N_NODES + 63) / 64;
    k_fused_mfma<<<gemm_blocks, 256, 0, stream>>>(T, Wf, b1, W2, b2, y);
}